// Round 3
// baseline (543.184 us; speedup 1.0000x reference)
//
#include <hip/hip_runtime.h>
#include <hip/hip_fp16.h>

#define EMB 128
#define CH  8      // item-table chunks (each ~3.2MB fp16, fits 4MB per-XCD L2)
#define UT  64     // users per tile/block in the main kernel

// ---------- fp32 -> fp16 item table ----------
__global__ __launch_bounds__(256) void convert_kernel(
    const float* __restrict__ src, __half* __restrict__ dst, int n8)
{
    int t = blockIdx.x * 256 + threadIdx.x;
    if (t >= n8) return;
    const float4* s = (const float4*)src + (size_t)t * 2;
    float4 f0 = s[0];
    float4 f1 = s[1];
    union { __half h[8]; uint4 u; } pk;
    pk.h[0] = __float2half_rn(f0.x); pk.h[1] = __float2half_rn(f0.y);
    pk.h[2] = __float2half_rn(f0.z); pk.h[3] = __float2half_rn(f0.w);
    pk.h[4] = __float2half_rn(f1.x); pk.h[5] = __float2half_rn(f1.y);
    pk.h[6] = __float2half_rn(f1.z); pk.h[7] = __float2half_rn(f1.w);
    ((uint4*)dst)[t] = pk.u;
}

// ---------- start[u] = first behavior with beh_user >= u (beh_user sorted) ----------
__global__ __launch_bounds__(256) void boundary_kernel(
    const int* __restrict__ beh_user, int* __restrict__ start,
    int n_beh, int n_users)
{
    int j = blockIdx.x * 256 + threadIdx.x;
    if (j >= n_beh) return;
    int cur  = beh_user[j];
    int prev = (j == 0) ? -1 : beh_user[j - 1];
    if (cur != prev) {
        for (int u = prev + 1; u <= cur; ++u) start[u] = j;
    }
    if (j == n_beh - 1) {
        for (int u = cur + 1; u <= n_users; ++u) start[u] = n_beh;
    }
}

// ---------- stable per-tile partition of behaviors by item chunk ----------
// One block per user-tile. Writes reordered (pack,cnt) into [s0,s1) of r_*,
// pack = (user_local << 24) | item_id. Stability preserves user-sorted order
// within each chunk bucket (perf nicety only; correctness is order-free).
__global__ __launch_bounds__(256) void bucket_kernel(
    const int*   __restrict__ start,
    const int*   __restrict__ beh_item,
    const float* __restrict__ beh_cnt,
    const int*   __restrict__ beh_user,
    int*         __restrict__ r_pack,
    float*       __restrict__ r_cnt,
    int*         __restrict__ seg_off,
    int n_users, int rows_per_chunk)
{
    const int t   = blockIdx.x;
    const int tid = threadIdx.x;
    const int u0  = t * UT;
    const int u1  = min(u0 + UT, n_users);
    const int s0  = start[u0];
    const int s1  = start[u1];
    const int n   = s1 - s0;
    const int ipt = (n + 255) / 256;
    const int es  = s0 + tid * ipt;
    const int ee  = min(es + ipt, s1);

    __shared__ int cnt[256][CH];   // 8 KB
    __shared__ int colsum[CH];
    __shared__ int base[CH + 1];

    #pragma unroll
    for (int c = 0; c < CH; ++c) cnt[tid][c] = 0;
    __syncthreads();

    for (int e = es; e < ee; ++e) {
        int c = beh_item[e] / rows_per_chunk;
        cnt[tid][c]++;
    }
    __syncthreads();

    if (tid < CH) {                 // column sums
        int s = 0;
        for (int i = 0; i < 256; ++i) s += cnt[i][tid];
        colsum[tid] = s;
    }
    __syncthreads();
    if (tid == 0) {                 // exclusive scan over buckets
        int run = 0;
        for (int c = 0; c < CH; ++c) { base[c] = run; run += colsum[c]; }
        base[CH] = run;             // == n
    }
    __syncthreads();
    if (tid < CH) {                 // per-column exclusive prefix across threads
        int run = 0;
        for (int i = 0; i < 256; ++i) { int v = cnt[i][tid]; cnt[i][tid] = run; run += v; }
    }
    __syncthreads();

    if (tid <= CH) seg_off[t * (CH + 1) + tid] = s0 + base[tid];

    for (int e = es; e < ee; ++e) {
        int it = beh_item[e];
        int c  = it / rows_per_chunk;
        int ul = beh_user[e] - u0;
        int d  = s0 + base[c] + cnt[tid][c];
        cnt[tid][c] = cnt[tid][c] + 1;
        r_pack[d] = (ul << 24) | it;
        r_cnt[d]  = beh_cnt[e];
    }
}

// ---------- persistent main kernel: 1024 blocks (4/CU), 64 users/block ----------
// Sweeps item chunks 0..CH-1; while a chunk is hot, gathers hit per-XCD L2.
__global__ __launch_bounds__(256, 4) void main_kernel(
    const int*    __restrict__ user_ids,
    const int*    __restrict__ group_ids,
    const int*    __restrict__ r_pack,
    const float*  __restrict__ r_cnt,
    const int*    __restrict__ seg_off,
    const __half* __restrict__ item_f16,
    const float*  __restrict__ user_table,
    float*        __restrict__ out,
    int n_users)
{
    const int t    = blockIdx.x;
    const int lane = threadIdx.x & 63;
    const int wave = threadIdx.x >> 6;

    __shared__ float acc[UT][EMB];   // 32 KB
    for (int i = threadIdx.x; i < UT * EMB; i += 256) ((float*)acc)[i] = 0.f;
    __syncthreads();

    const int segs0 = t * (CH + 1);
    const __half* itp = item_f16 + lane * 2;

    for (int c = 0; c < CH; ++c) {
        int a   = seg_off[segs0 + c];
        int b   = seg_off[segs0 + c + 1];
        int len = b - a;
        int per = (len + 3) >> 2;
        int w0  = a + wave * per;
        int w1  = min(w0 + per, b);

        float2 racc = make_float2(0.f, 0.f);
        int    cur  = -1;

        int e = w0;
        for (; e + 4 <= w1; e += 4) {
            int   p0 = r_pack[e],     p1 = r_pack[e + 1];
            int   p2 = r_pack[e + 2], p3 = r_pack[e + 3];
            float c0 = r_cnt[e],      c1 = r_cnt[e + 1];
            float c2 = r_cnt[e + 2],  c3 = r_cnt[e + 3];
            __half2 h0 = *(const __half2*)(itp + (size_t)(p0 & 0xFFFFFF) * EMB);
            __half2 h1 = *(const __half2*)(itp + (size_t)(p1 & 0xFFFFFF) * EMB);
            __half2 h2 = *(const __half2*)(itp + (size_t)(p2 & 0xFFFFFF) * EMB);
            __half2 h3 = *(const __half2*)(itp + (size_t)(p3 & 0xFFFFFF) * EMB);
            #define ACC_STEP(P, CC, H)                                              \
            {                                                                        \
                int ul = (P) >> 24;                                                  \
                if (ul != cur) {                                                     \
                    if (cur >= 0) {                                                  \
                        atomicAdd(&acc[cur][lane * 2],     racc.x);                  \
                        atomicAdd(&acc[cur][lane * 2 + 1], racc.y);                  \
                    }                                                                \
                    cur = ul; racc = make_float2(0.f, 0.f);                          \
                }                                                                    \
                float2 v = __half22float2(H);                                        \
                racc.x = fmaf(v.x, (CC), racc.x);                                    \
                racc.y = fmaf(v.y, (CC), racc.y);                                    \
            }
            ACC_STEP(p0, c0, h0)
            ACC_STEP(p1, c1, h1)
            ACC_STEP(p2, c2, h2)
            ACC_STEP(p3, c3, h3)
        }
        for (; e < w1; ++e) {
            int   p  = r_pack[e];
            float cc = r_cnt[e];
            __half2 h = *(const __half2*)(itp + (size_t)(p & 0xFFFFFF) * EMB);
            ACC_STEP(p, cc, h)
        }
        if (cur >= 0) {
            atomicAdd(&acc[cur][lane * 2],     racc.x);
            atomicAdd(&acc[cur][lane * 2 + 1], racc.y);
        }
        #undef ACC_STEP
    }
    __syncthreads();

    // Epilogue: multiply by user embedding, run-merge by (sorted) group, atomic to out.
    int    gprev = -1;
    float2 osum  = make_float2(0.f, 0.f);
    for (int u = wave * 16; u < wave * 16 + 16; ++u) {
        int user = t * UT + u;
        if (user >= n_users) break;
        float2 v = make_float2(acc[u][lane * 2], acc[u][lane * 2 + 1]);
        int uid = user_ids[user];
        float2 ue = make_float2(0.f, 0.f);
        if (uid != 0) ue = *(const float2*)(user_table + (size_t)uid * EMB + lane * 2);
        v.x *= ue.x; v.y *= ue.y;
        int g = group_ids[user];
        if (g != gprev) {
            if (gprev >= 0) {
                atomicAdd(&out[(size_t)gprev * EMB + lane * 2],     osum.x);
                atomicAdd(&out[(size_t)gprev * EMB + lane * 2 + 1], osum.y);
            }
            gprev = g; osum = make_float2(0.f, 0.f);
        }
        osum.x += v.x; osum.y += v.y;
    }
    if (gprev >= 0) {
        atomicAdd(&out[(size_t)gprev * EMB + lane * 2],     osum.x);
        atomicAdd(&out[(size_t)gprev * EMB + lane * 2 + 1], osum.y);
    }
}

// ---------- round-2 fallback (used only if ws too small) ----------
__global__ __launch_bounds__(256) void per_user_kernel(
    const int*   __restrict__ user_ids,
    const int*   __restrict__ group_ids,
    const int*   __restrict__ beh_item,
    const float* __restrict__ beh_cnt,
    const int*   __restrict__ beh_user,
    const float* __restrict__ user_table,
    const float* __restrict__ item_f32,
    float*       __restrict__ out,
    int n_users, int n_beh)
{
    const int lane = threadIdx.x & 63;
    const int wave = threadIdx.x >> 6;
    const int user = blockIdx.x * 4 + wave;
    float2 acc = make_float2(0.f, 0.f);
    int g = -1;
    if (user < n_users) {
        int lo = 0, hi = n_beh;
        while (lo < hi) { int m = (lo + hi) >> 1; if (beh_user[m] < user) lo = m + 1; else hi = m; }
        int s = lo; hi = n_beh;
        while (lo < hi) { int m = (lo + hi) >> 1; if (beh_user[m] <= user) lo = m + 1; else hi = m; }
        int e = lo;
        for (int j = s; j < e; ++j) {
            int   b = beh_item[j];
            float c = beh_cnt[j];
            float2 v = *(const float2*)(item_f32 + (size_t)b * EMB + lane * 2);
            acc.x = fmaf(v.x, c, acc.x);
            acc.y = fmaf(v.y, c, acc.y);
        }
        int uid = user_ids[user];
        float2 ue = make_float2(0.f, 0.f);
        if (uid != 0) ue = *(const float2*)(user_table + (size_t)uid * EMB + lane * 2);
        acc.x *= ue.x; acc.y *= ue.y;
        g = group_ids[user];
    }
    if (g >= 0) {
        atomicAdd(&out[(size_t)g * EMB + lane * 2],     acc.x);
        atomicAdd(&out[(size_t)g * EMB + lane * 2 + 1], acc.y);
    }
}

extern "C" void kernel_launch(void* const* d_in, const int* in_sizes, int n_in,
                              void* d_out, int out_size, void* d_ws, size_t ws_size,
                              hipStream_t stream) {
    const int*   user_ids   = (const int*)  d_in[0];
    const int*   group_ids  = (const int*)  d_in[1];
    const int*   beh_item   = (const int*)  d_in[2];
    const float* beh_cnt    = (const float*)d_in[3];
    const int*   beh_user   = (const int*)  d_in[4];
    const float* user_table = (const float*)d_in[5];
    const float* item_table = (const float*)d_in[6];

    const int n_users = in_sizes[0];
    const int n_beh   = in_sizes[2];
    const int item_n  = in_sizes[6] / EMB;
    const int nt      = (n_users + UT - 1) / UT;
    const int rpc     = (item_n + CH - 1) / CH;

    float* out = (float*)d_out;
    hipMemsetAsync(out, 0, (size_t)out_size * sizeof(float), stream);

    // ws layout: start | item_f16 | r_pack | r_cnt | seg_off   (all 256B aligned)
    size_t off = 0;
    auto take = [&](size_t bytes) { size_t o = off; off = (off + bytes + 255) & ~(size_t)255; return o; };
    size_t o_start = take((size_t)(n_users + 1) * sizeof(int));
    size_t o_f16   = take((size_t)item_n * EMB * sizeof(__half));
    size_t o_pack  = take((size_t)n_beh * sizeof(int));
    size_t o_cnt   = take((size_t)n_beh * sizeof(float));
    size_t o_seg   = take((size_t)nt * (CH + 1) * sizeof(int));

    bool fits = (off <= ws_size) && (item_n < (1 << 24)) && (n_beh > 0);

    if (!fits) {
        int ublocks = (n_users + 3) / 4;
        per_user_kernel<<<ublocks, 256, 0, stream>>>(
            user_ids, group_ids, beh_item, beh_cnt, beh_user,
            user_table, item_table, out, n_users, n_beh);
        return;
    }

    int*    start    = (int*)   ((char*)d_ws + o_start);
    __half* item_f16 = (__half*)((char*)d_ws + o_f16);
    int*    r_pack   = (int*)   ((char*)d_ws + o_pack);
    float*  r_cnt    = (float*) ((char*)d_ws + o_cnt);
    int*    seg_off  = (int*)   ((char*)d_ws + o_seg);

    boundary_kernel<<<(n_beh + 255) / 256, 256, 0, stream>>>(beh_user, start, n_beh, n_users);

    int n8 = (item_n * EMB) / 8;
    convert_kernel<<<(n8 + 255) / 256, 256, 0, stream>>>(item_table, item_f16, n8);

    bucket_kernel<<<nt, 256, 0, stream>>>(
        start, beh_item, beh_cnt, beh_user, r_pack, r_cnt, seg_off, n_users, rpc);

    main_kernel<<<nt, 256, 0, stream>>>(
        user_ids, group_ids, r_pack, r_cnt, seg_off,
        item_f16, user_table, out, n_users);
}

// Round 4
// 245.030 us; speedup vs baseline: 2.2168x; 2.2168x over previous
//
#include <hip/hip_runtime.h>
#include <hip/hip_fp16.h>

#define EMB 128

// ---------- fp32 -> fp16 item table ----------
__global__ __launch_bounds__(256) void convert_kernel(
    const float* __restrict__ src, __half* __restrict__ dst, int n8)
{
    int t = blockIdx.x * 256 + threadIdx.x;
    if (t >= n8) return;
    const float4* s = (const float4*)src + (size_t)t * 2;
    float4 f0 = s[0];
    float4 f1 = s[1];
    union { __half h[8]; uint4 u; } pk;
    pk.h[0] = __float2half_rn(f0.x); pk.h[1] = __float2half_rn(f0.y);
    pk.h[2] = __float2half_rn(f0.z); pk.h[3] = __float2half_rn(f0.w);
    pk.h[4] = __float2half_rn(f1.x); pk.h[5] = __float2half_rn(f1.y);
    pk.h[6] = __float2half_rn(f1.z); pk.h[7] = __float2half_rn(f1.w);
    ((uint4*)dst)[t] = pk.u;
}

// ---------- start[u] = first behavior with beh_user >= u (beh_user sorted) ----------
__global__ __launch_bounds__(256) void boundary_kernel(
    const int* __restrict__ beh_user, int* __restrict__ start,
    int n_beh, int n_users)
{
    int j = blockIdx.x * 256 + threadIdx.x;
    if (j >= n_beh) return;
    int cur  = beh_user[j];
    int prev = (j == 0) ? -1 : beh_user[j - 1];
    if (cur != prev) {
        for (int u = prev + 1; u <= cur; ++u) start[u] = j;
    }
    if (j == n_beh - 1) {
        for (int u = cur + 1; u <= n_users; ++u) start[u] = n_beh;
    }
}

// One wave per user. Row layout: 32 lanes per row, each lane owns 4 dims
// (8 B fp16). Lane-half 0 (lanes 0-31) processes behaviors [j, j+8),
// half 1 (lanes 32-63) processes [j+8, j+16) -> one load instr fetches TWO
// rows; unroll 8 => 16 rows in flight per wave (2x round-2 MLP).
// Halves combined once per user via shfl_xor(32).
__global__ __launch_bounds__(256) void per_user_kernel(
    const int*    __restrict__ user_ids,
    const int*    __restrict__ group_ids,
    const int*    __restrict__ beh_item,
    const float*  __restrict__ beh_cnt,
    const int*    __restrict__ beh_user,   // binary-search fallback only
    const float*  __restrict__ user_table,
    const __half* __restrict__ item_f16,
    const int*    __restrict__ start,      // may be null -> binary search
    float*        __restrict__ out,
    int n_users, int n_beh)
{
    const int lane = threadIdx.x & 63;
    const int half = lane >> 5;   // 0 or 1
    const int sub  = lane & 31;   // lane within half; owns dims [sub*4, sub*4+4)
    const int wave = threadIdx.x >> 6;
    const int user = blockIdx.x * 4 + wave;

    __shared__ float lds_acc[EMB];
    __shared__ int   lds_grp[4];
    if (threadIdx.x < EMB) lds_acc[threadIdx.x] = 0.0f;

    float4 acc = make_float4(0.f, 0.f, 0.f, 0.f);
    int g = -1;

    if (user < n_users) {
        int s, e;
        if (start) {
            s = start[user];
            e = start[user + 1];
        } else {
            int lo = 0, hi = n_beh;
            while (lo < hi) { int m = (lo + hi) >> 1; if (beh_user[m] < user) lo = m + 1; else hi = m; }
            s = lo;
            hi = n_beh;
            while (lo < hi) { int m = (lo + hi) >> 1; if (beh_user[m] <= user) lo = m + 1; else hi = m; }
            e = lo;
        }

        const __half* itp = item_f16 + sub * 4;   // this lane's 8B slice of any row

        int j = s;
        // main loop: 16 behaviors per iteration (8 per half)
        for (; j + 16 <= e; j += 16) {
            const int base = j + half * 8;
            int   bidx[8];
            float bcnt[8];
            #pragma unroll
            for (int k = 0; k < 8; ++k) { bidx[k] = beh_item[base + k]; bcnt[k] = beh_cnt[base + k]; }
            uint2 raw[8];
            #pragma unroll
            for (int k = 0; k < 8; ++k)
                raw[k] = *(const uint2*)(itp + (size_t)bidx[k] * EMB);
            #pragma unroll
            for (int k = 0; k < 8; ++k) {
                float2 f01 = __half22float2(*(const __half2*)&raw[k].x);
                float2 f23 = __half22float2(*(const __half2*)&raw[k].y);
                float  c   = bcnt[k];
                acc.x = fmaf(f01.x, c, acc.x);
                acc.y = fmaf(f01.y, c, acc.y);
                acc.z = fmaf(f23.x, c, acc.z);
                acc.w = fmaf(f23.y, c, acc.w);
            }
        }
        // tail: 2 behaviors per iteration (half h takes j+h), masked
        for (; j < e; j += 2) {
            int   jj = j + half;
            int   bi = 0;
            float c  = 0.f;
            if (jj < e) { bi = beh_item[jj]; c = beh_cnt[jj]; }
            uint2 raw = *(const uint2*)(itp + (size_t)bi * EMB);
            float2 f01 = __half22float2(*(const __half2*)&raw.x);
            float2 f23 = __half22float2(*(const __half2*)&raw.y);
            acc.x = fmaf(f01.x, c, acc.x);
            acc.y = fmaf(f01.y, c, acc.y);
            acc.z = fmaf(f23.x, c, acc.z);
            acc.w = fmaf(f23.y, c, acc.w);
        }

        // combine the two halves (lanes L and L^32 hold partials of same dims)
        acc.x += __shfl_xor(acc.x, 32, 64);
        acc.y += __shfl_xor(acc.y, 32, 64);
        acc.z += __shfl_xor(acc.z, 32, 64);
        acc.w += __shfl_xor(acc.w, 32, 64);

        int uid = user_ids[user];
        float4 ue = make_float4(0.f, 0.f, 0.f, 0.f);
        if (uid != 0) ue = *(const float4*)(user_table + (size_t)uid * EMB + sub * 4);
        acc.x *= ue.x; acc.y *= ue.y; acc.z *= ue.z; acc.w *= ue.w;

        g = group_ids[user];
    }

    // lane L<32 writes dims sub*4+{0,1}; lane L>=32 writes sub*4+{2,3}
    const int   d0 = sub * 4 + half * 2;
    const float v0 = half ? acc.z : acc.x;
    const float v1 = half ? acc.w : acc.y;

    if (lane == 0) lds_grp[wave] = g;
    __syncthreads();

    int g0 = lds_grp[0];
    bool same = (g0 >= 0) && (lds_grp[1] == g0) && (lds_grp[2] == g0) && (lds_grp[3] == g0);
    if (same) {
        atomicAdd(&lds_acc[d0],     v0);
        atomicAdd(&lds_acc[d0 + 1], v1);
        __syncthreads();
        if (wave == 0) {
            atomicAdd(&out[(size_t)g0 * EMB + d0],     lds_acc[d0]);
            atomicAdd(&out[(size_t)g0 * EMB + d0 + 1], lds_acc[d0 + 1]);
        }
    } else if (g >= 0) {
        atomicAdd(&out[(size_t)g * EMB + d0],     v0);
        atomicAdd(&out[(size_t)g * EMB + d0 + 1], v1);
    }
}

// ---------- fp32 fallback (ws too small for fp16 table) ----------
__global__ __launch_bounds__(256) void per_user_f32_kernel(
    const int*   __restrict__ user_ids,
    const int*   __restrict__ group_ids,
    const int*   __restrict__ beh_item,
    const float* __restrict__ beh_cnt,
    const int*   __restrict__ beh_user,
    const float* __restrict__ user_table,
    const float* __restrict__ item_f32,
    float*       __restrict__ out,
    int n_users, int n_beh)
{
    const int lane = threadIdx.x & 63;
    const int wave = threadIdx.x >> 6;
    const int user = blockIdx.x * 4 + wave;
    float2 acc = make_float2(0.f, 0.f);
    int g = -1;
    if (user < n_users) {
        int lo = 0, hi = n_beh;
        while (lo < hi) { int m = (lo + hi) >> 1; if (beh_user[m] < user) lo = m + 1; else hi = m; }
        int s = lo; hi = n_beh;
        while (lo < hi) { int m = (lo + hi) >> 1; if (beh_user[m] <= user) lo = m + 1; else hi = m; }
        int e = lo;
        for (int j = s; j < e; ++j) {
            int   b = beh_item[j];
            float c = beh_cnt[j];
            float2 v = *(const float2*)(item_f32 + (size_t)b * EMB + lane * 2);
            acc.x = fmaf(v.x, c, acc.x);
            acc.y = fmaf(v.y, c, acc.y);
        }
        int uid = user_ids[user];
        float2 ue = make_float2(0.f, 0.f);
        if (uid != 0) ue = *(const float2*)(user_table + (size_t)uid * EMB + lane * 2);
        acc.x *= ue.x; acc.y *= ue.y;
        g = group_ids[user];
    }
    if (g >= 0) {
        atomicAdd(&out[(size_t)g * EMB + lane * 2],     acc.x);
        atomicAdd(&out[(size_t)g * EMB + lane * 2 + 1], acc.y);
    }
}

extern "C" void kernel_launch(void* const* d_in, const int* in_sizes, int n_in,
                              void* d_out, int out_size, void* d_ws, size_t ws_size,
                              hipStream_t stream) {
    const int*   user_ids   = (const int*)  d_in[0];
    const int*   group_ids  = (const int*)  d_in[1];
    const int*   beh_item   = (const int*)  d_in[2];
    const float* beh_cnt    = (const float*)d_in[3];
    const int*   beh_user   = (const int*)  d_in[4];
    const float* user_table = (const float*)d_in[5];
    const float* item_table = (const float*)d_in[6];

    const int n_users = in_sizes[0];
    const int n_beh   = in_sizes[2];
    const int item_n  = in_sizes[6] / EMB;

    float* out = (float*)d_out;
    hipMemsetAsync(out, 0, (size_t)out_size * sizeof(float), stream);

    // ws layout: start | item_f16 (256B aligned)
    size_t start_bytes = (size_t)(n_users + 1) * sizeof(int);
    size_t f16_off     = (start_bytes + 255) & ~(size_t)255;
    size_t f16_bytes   = (size_t)item_n * EMB * sizeof(__half);

    if (ws_size < f16_off + f16_bytes) {
        int ublocks = (n_users + 3) / 4;
        per_user_f32_kernel<<<ublocks, 256, 0, stream>>>(
            user_ids, group_ids, beh_item, beh_cnt, beh_user,
            user_table, item_table, out, n_users, n_beh);
        return;
    }

    int*    start    = (int*)d_ws;
    __half* item_f16 = (__half*)((char*)d_ws + f16_off);

    boundary_kernel<<<(n_beh + 255) / 256, 256, 0, stream>>>(beh_user, start, n_beh, n_users);

    int n8 = (item_n * EMB) / 8;
    convert_kernel<<<(n8 + 255) / 256, 256, 0, stream>>>(item_table, item_f16, n8);

    int ublocks = (n_users + 3) / 4;
    per_user_kernel<<<ublocks, 256, 0, stream>>>(
        user_ids, group_ids, beh_item, beh_cnt, beh_user,
        user_table, item_f16, start, out, n_users, n_beh);
}